// Round 5
// baseline (251.484 us; speedup 1.0000x reference)
//
#include <hip/hip_runtime.h>
#include <hip/hip_bf16.h>

#define B_ 2
#define S_ 2048
#define D_ 1024
#define H_ 16
#define KV_ 4
#define HD_ 64
#define G_ (H_ / KV_)
#define NCAT 2816          // 2*H*HD + 2*KV*HD + KV*HD
#define VOFF 2560          // col offset of V block in fused QKV output

typedef __attribute__((ext_vector_type(8))) short short8;
typedef __attribute__((ext_vector_type(4))) short short4v;
typedef __attribute__((ext_vector_type(4))) float floatx4;

using gvoid_p = const __attribute__((address_space(1))) void*;
using lvoid_p = __attribute__((address_space(3))) void*;

__device__ inline void gload_lds16(const short* g, short* l) {
    __builtin_amdgcn_global_load_lds((gvoid_p)(const void*)g, (lvoid_p)(void*)l, 16, 0, 0);
}

// pack two f32 -> one dword of two bf16 (T12 recipe: no builtin on gfx950)
__device__ inline int cvt_pk_bf16(float lo, float hi) {
    int r;
    asm volatile("v_cvt_pk_bf16_f32 %0, %1, %2" : "=v"(r) : "v"(lo), "v"(hi));
    return r;
}

// ---------------- fp32 -> bf16 convert ----------------
__global__ void cvt_bf16_kernel(const float* __restrict__ in,
                                __hip_bfloat16* __restrict__ out, int n) {
    int i = blockIdx.x * blockDim.x + threadIdx.x;
    if (i < n) out[i] = __float2bfloat16(in[i]);
}

// ---------------- NT GEMM, LDS double-buffered with counted vmcnt (T3 2-phase) ----------
// C(MxN) = A(MxK) * B(NxK)^T, bf16 in, OutT out. 128x128 tile, BK=32, 4 waves.
template <typename OutT>
__global__ __launch_bounds__(256) void gemm_bt_lds(const short* __restrict__ A,
                                                   const short* __restrict__ Bm,
                                                   OutT* __restrict__ C,
                                                   int M, int N, int K) {
    __shared__ __align__(16) short As[2][128 * 32];
    __shared__ __align__(16) short Bs[2][128 * 32];
    int tid = threadIdx.x;
    int wid = tid >> 6, lane = tid & 63;
    int wr = wid >> 1, wc = wid & 1;
    int r = lane & 15, kq = lane >> 4;
    long m0 = (long)blockIdx.y * 128;
    long n0 = (long)blockIdx.x * 128;

    const short* gA0 = A + (m0 + (tid >> 2)) * (long)K + (tid & 3) * 8;
    const short* gA1 = A + (m0 + 64 + (tid >> 2)) * (long)K + (tid & 3) * 8;
    const short* gB0 = Bm + (n0 + (tid >> 2)) * (long)K + (tid & 3) * 8;
    const short* gB1 = Bm + (n0 + 64 + (tid >> 2)) * (long)K + (tid & 3) * 8;

    auto stage = [&](int buf, int k0) {
        gload_lds16(gA0 + k0, &As[buf][wid * 512]);
        gload_lds16(gA1 + k0, &As[buf][2048 + wid * 512]);
        gload_lds16(gB0 + k0, &Bs[buf][wid * 512]);
        gload_lds16(gB1 + k0, &Bs[buf][2048 + wid * 512]);
    };

    floatx4 acc[4][4];
#pragma unroll
    for (int i = 0; i < 4; ++i)
#pragma unroll
        for (int j = 0; j < 4; ++j) acc[i][j] = {0.f, 0.f, 0.f, 0.f};

    int nt = K >> 5;
    stage(0, 0);
    for (int t = 0; t < nt; ++t) {
        int cur = t & 1;
        __builtin_amdgcn_s_barrier();           // prev compute's reads of buf[cur^1] done
        if (t + 1 < nt) {
            stage(cur ^ 1, (t + 1) << 5);
            asm volatile("s_waitcnt vmcnt(4)" ::: "memory");   // tile t landed; t+1 in flight
        } else {
            asm volatile("s_waitcnt vmcnt(0)" ::: "memory");
        }
        __builtin_amdgcn_sched_barrier(0);
        __builtin_amdgcn_s_barrier();           // all waves see buf[cur]
        short8 a[4], b[4];
#pragma unroll
        for (int mi = 0; mi < 4; ++mi)
            a[mi] = *(const short8*)&As[cur][(wr * 64 + mi * 16 + r) * 32 + kq * 8];
#pragma unroll
        for (int ni = 0; ni < 4; ++ni)
            b[ni] = *(const short8*)&Bs[cur][(wc * 64 + ni * 16 + r) * 32 + kq * 8];
#pragma unroll
        for (int mi = 0; mi < 4; ++mi)
#pragma unroll
            for (int ni = 0; ni < 4; ++ni)
                acc[mi][ni] = __builtin_amdgcn_mfma_f32_16x16x32_bf16(
                    a[mi], b[ni], acc[mi][ni], 0, 0, 0);
    }
    int col_l = lane & 15, row_l = (lane >> 4) * 4;
#pragma unroll
    for (int mi = 0; mi < 4; ++mi)
#pragma unroll
        for (int ni = 0; ni < 4; ++ni) {
            long col = n0 + wc * 64 + ni * 16 + col_l;
            long row0 = m0 + wr * 64 + mi * 16 + row_l;
#pragma unroll
            for (int j = 0; j < 4; ++j) {
                float v = acc[mi][ni][j];
                if constexpr (__is_same(OutT, float))
                    C[(row0 + j) * N + col] = v;
                else
                    C[(row0 + j) * N + col] = __float2bfloat16(v);
            }
        }
}

// ---------------- RMSNorm (per-64) + RoPE, strided bf16 in -> packed bf16 out ----------------
__global__ void norm_rope_kernel(const __hip_bfloat16* __restrict__ buf,
                                 __hip_bfloat16* __restrict__ outb,
                                 const float* __restrict__ freqs,
                                 const float* __restrict__ w, int nvec, int nh,
                                 int tstride, int colbase) {
    int gt = blockIdx.x * blockDim.x + threadIdx.x;
    int gw = gt >> 6;
    int lane = gt & 63;
    if (gw >= nvec) return;
    int t = gw / (nh * 2);
    int rem = gw - t * (nh * 2);
    int s = t & (S_ - 1);
    const __hip_bfloat16* v = buf + (long)t * tstride + colbase + rem * 64;
    float x = __bfloat162float(v[lane]);
    float ss = x * x;
#pragma unroll
    for (int off = 32; off; off >>= 1) ss += __shfl_xor(ss, off);
    float r = rsqrtf(ss * (1.f / 64.f) + 1e-6f);
    x = x * r * w[lane];
    int i = lane >> 1;
    float c  = freqs[(s * (HD_ / 2) + i) * 2];
    float sn = freqs[(s * (HD_ / 2) + i) * 2 + 1];
    float p = __shfl_xor(x, 1);
    float y = (lane & 1) ? fmaf(p, sn, x * c) : fmaf(x, c, -(p * sn));
    outb[(long)gw * 64 + lane] = __float2bfloat16(y);
}

// ---------------- V transpose: qkvb bf16 [t][NCAT] -> vT bf16 [b][kv][d][s] ----------------
__global__ __launch_bounds__(256) void v_transpose_kernel(const short* __restrict__ src,
                                                          short* __restrict__ dst) {
    __shared__ short ls[64][72];
    int s0 = blockIdx.x * 64;
    int kv = blockIdx.y, b = blockIdx.z;
    int tid = threadIdx.x;
    const short* base = src + ((long)(b * S_ + s0)) * NCAT + VOFF + kv * 64;
    {
        int rr = tid >> 2, cc = (tid & 3) * 16;
        *(short8*)&ls[rr][cc]     = *(const short8*)(base + (long)rr * NCAT + cc);
        *(short8*)&ls[rr][cc + 8] = *(const short8*)(base + (long)rr * NCAT + cc + 8);
    }
    __syncthreads();
    short* ob = dst + ((long)(b * KV_ + kv) * 64) * S_ + s0;
    {
        int d = tid >> 2, sl = (tid & 3) * 16;
        short8 o0, o1;
#pragma unroll
        for (int e = 0; e < 8; ++e) { o0[e] = ls[sl + e][d]; o1[e] = ls[sl + 8 + e][d]; }
        *(short8*)(ob + (long)d * S_ + sl)     = o0;
        *(short8*)(ob + (long)d * S_ + sl + 8) = o1;
    }
}

// ---------------- differential causal attention (MFMA flash, T14 async-stage) ----------------
// grid (32, H, B); qt = x ^ (31*((h>>3)^b)) -> every CU gets equal causal work.
// Swapped QK^T (S^T = mfma(K,Q)): lane (r,kq) holds P[q=r][k=16nt+4kq+j] = the
// 16x16x16 A-frag layout -> PV with no cross-lane traffic. Fixed-offset softmax.
// Staging: next K/V tile global->regs issued under current tile's compute (T14);
// raw s_barrier + lgkmcnt(0) only (global loads stay in flight across barriers).
__global__ __launch_bounds__(256, 4) void attn_kernel(const short* __restrict__ qb,
                                                      const short* __restrict__ kbuf,
                                                      const short* __restrict__ vtb,
                                                      __hip_bfloat16* __restrict__ ob,
                                                      const float* __restrict__ lam_p) {
    __shared__ __align__(16) short k1s[64][72];
    __shared__ __align__(16) short k2s[64][72];
    __shared__ __align__(16) short vts[64][76];

    int tid = threadIdx.x, lane = tid & 63;
    int b = blockIdx.z, h = blockIdx.y, kv = h / G_;
    int qt = (int)blockIdx.x ^ (31 * (((h >> 3) ^ b) & 1));
    int q0 = qt * 64 + (tid >> 6) * 16;
    int r = lane & 15, kq = lane >> 4;
    float lam = lam_p[0];

    short8 qa[2][2];
    {
        const short* qrow = qb + ((long)(b * S_ + q0 + r) * H_ + h) * 128;
        qa[0][0] = *(const short8*)(qrow + kq * 8);
        qa[0][1] = *(const short8*)(qrow + 32 + kq * 8);
        qa[1][0] = *(const short8*)(qrow + 64 + kq * 8);
        qa[1][1] = *(const short8*)(qrow + 96 + kq * 8);
    }

    floatx4 acc[2][4];
#pragma unroll
    for (int m = 0; m < 2; ++m)
#pragma unroll
        for (int dt = 0; dt < 4; ++dt) acc[m][dt] = {0.f, 0.f, 0.f, 0.f};
    float lsum[2] = {0.f, 0.f};

    const short* vbase = vtb + (long)(b * KV_ + kv) * 64 * S_;
    const float c1 = 0.18033688f, c2 = 6.40607e-5f, c3 = 4.9243e-9f, zoff = -17.3123405f;

    // stage registers (K: 4 x short8, V: 2 x short8)
    short8 rk[4], rv[2];
    int krr = tid >> 4, kcc = tid & 15;          // K chunk base: rows krr+{0,16,32,48}
    int vrr = tid >> 3, vcc = tid & 7;           // V chunk base: rows vrr+{0,32}
    auto load_tile = [&](int kb) {
#pragma unroll
        for (int i = 0; i < 4; ++i)
            rk[i] = *(const short8*)(kbuf +
                ((long)(b * S_ + kb + krr + i * 16) * KV_ + kv) * 128 + kcc * 8);
#pragma unroll
        for (int i = 0; i < 2; ++i)
            rv[i] = *(const short8*)(vbase + (long)(vrr + i * 32) * S_ + kb + vcc * 8);
    };
    auto write_tile = [&]() {
#pragma unroll
        for (int i = 0; i < 4; ++i) {
            if (kcc < 8) *(short8*)&k1s[krr + i * 16][kcc * 8] = rk[i];
            else         *(short8*)&k2s[krr + i * 16][(kcc - 8) * 8] = rk[i];
        }
#pragma unroll
        for (int i = 0; i < 2; ++i)
            *(short8*)&vts[vrr + i * 32][vcc * 8] = rv[i];
    };

    int last_kb = qt * 64;
    load_tile(0);
    for (int kb = 0; kb <= last_kb; kb += 64) {
        __builtin_amdgcn_s_barrier();            // prev tile's LDS reads done
        write_tile();                            // (compiler waits vmcnt for rk/rv)
        if (kb + 64 <= last_kb) load_tile(kb + 64);   // prefetch: stays in flight
        asm volatile("s_waitcnt lgkmcnt(0)" ::: "memory");
        __builtin_amdgcn_sched_barrier(0);
        __builtin_amdgcn_s_barrier();            // tile visible to all waves

        bool domask = (kb == last_kb);
#pragma unroll
        for (int m = 0; m < 2; ++m) {
            const short (*ks)[72] = m ? k2s : k1s;
            floatx4 sacc[4];
#pragma unroll
            for (int nt = 0; nt < 4; ++nt) {
                sacc[nt] = {0.f, 0.f, 0.f, 0.f};
                short8 a0 = *(const short8*)&ks[nt * 16 + r][kq * 8];
                short8 a1 = *(const short8*)&ks[nt * 16 + r][32 + kq * 8];
                sacc[nt] = __builtin_amdgcn_mfma_f32_16x16x32_bf16(a0, qa[m][0], sacc[nt], 0, 0, 0);
                sacc[nt] = __builtin_amdgcn_mfma_f32_16x16x32_bf16(a1, qa[m][1], sacc[nt], 0, 0, 0);
            }
            short4v pa[4];
#pragma unroll
            for (int nt = 0; nt < 4; ++nt) {
                float p[4];
#pragma unroll
                for (int j = 0; j < 4; ++j) {
                    float t = sacc[nt][j] * c1;
                    float t2 = t * t;
                    float u = fmaf(c3, t2, -c2);
                    float wv = fmaf(u, t2, 1.0f);
                    float z = fmaf(t, wv, zoff);
                    p[j] = __builtin_amdgcn_exp2f(z);
                    if (domask && (kb + nt * 16 + kq * 4 + j > q0 + r)) p[j] = 0.f;
                    lsum[m] += p[j];
                }
                int lo = cvt_pk_bf16(p[0], p[1]);
                int hi = cvt_pk_bf16(p[2], p[3]);
                pa[nt][0] = (short)(lo & 0xffff);
                pa[nt][1] = (short)((unsigned)lo >> 16);
                pa[nt][2] = (short)(hi & 0xffff);
                pa[nt][3] = (short)((unsigned)hi >> 16);
            }
#pragma unroll
            for (int dt = 0; dt < 4; ++dt) {
#pragma unroll
                for (int nt = 0; nt < 4; ++nt) {
                    short4v vb = *(const short4v*)&vts[dt * 16 + r][16 * nt + 4 * kq];
                    acc[m][dt] = __builtin_amdgcn_mfma_f32_16x16x16bf16_1k(
                        pa[nt], vb, acc[m][dt], 0, 0, 0);
                }
            }
        }
    }

    float L0 = lsum[0], L1 = lsum[1];
    L0 += __shfl_xor(L0, 16); L0 += __shfl_xor(L0, 32);
    L1 += __shfl_xor(L1, 16); L1 += __shfl_xor(L1, 32);

#pragma unroll
    for (int j = 0; j < 4; ++j) {
        float i1 = 1.f / __shfl(L0, kq * 4 + j);
        float i2 = lam / __shfl(L1, kq * 4 + j);
        int qr = q0 + kq * 4 + j;
        __hip_bfloat16* orow = ob + ((long)(b * S_ + qr) * H_ + h) * 64;
#pragma unroll
        for (int dt = 0; dt < 4; ++dt) {
            float val = acc[0][dt][j] * i1 - acc[1][dt][j] * i2;
            orow[dt * 16 + r] = __float2bfloat16(val);
        }
    }
}

// ---------------- launch ----------------
extern "C" void kernel_launch(void* const* d_in, const int* in_sizes, int n_in,
                              void* d_out, int out_size, void* d_ws, size_t ws_size,
                              hipStream_t stream) {
    const float* x     = (const float*)d_in[0];
    const float* freqs = (const float*)d_in[1];
    const float* wq    = (const float*)d_in[2];
    const float* wk    = (const float*)d_in[3];
    const float* wv    = (const float*)d_in[4];
    const float* wo    = (const float*)d_in[5];
    const float* qnw   = (const float*)d_in[6];
    const float* knw   = (const float*)d_in[7];
    const float* lam   = (const float*)d_in[8];
    float* out = (float*)d_out;

    const int T = B_ * S_;
    char* ws = (char*)d_ws;
    size_t off = 0;
    auto alloc = [&](size_t bytes) {
        void* p = ws + off;
        off += (bytes + 255) & ~(size_t)255;
        return p;
    };
    __hip_bfloat16* xb   = (__hip_bfloat16*)alloc((size_t)T * D_ * 2);
    __hip_bfloat16* wcat = (__hip_bfloat16*)alloc((size_t)NCAT * D_ * 2);
    __hip_bfloat16* wob  = (__hip_bfloat16*)alloc((size_t)D_ * D_ * 2);
    __hip_bfloat16* qkvb = (__hip_bfloat16*)alloc((size_t)T * NCAT * 2);
    __hip_bfloat16* qb16 = (__hip_bfloat16*)alloc((size_t)T * 2 * H_ * HD_ * 2);
    __hip_bfloat16* kb16 = (__hip_bfloat16*)alloc((size_t)T * 2 * KV_ * HD_ * 2);
    __hip_bfloat16* vT   = (__hip_bfloat16*)alloc((size_t)B_ * KV_ * HD_ * S_ * 2);
    __hip_bfloat16* aob  = xb;   // xb dead after QKV GEMM; same size

    auto cvt = [&](const float* src, __hip_bfloat16* dst, long n) {
        cvt_bf16_kernel<<<(n + 255) / 256, 256, 0, stream>>>(src, dst, (int)n);
    };
    cvt(x, xb, (long)T * D_);
    cvt(wq, wcat, (long)2 * H_ * HD_ * D_);
    cvt(wk, wcat + (size_t)2 * H_ * HD_ * D_, (long)2 * KV_ * HD_ * D_);
    cvt(wv, wcat + (size_t)(2 * H_ * HD_ + 2 * KV_ * HD_) * D_, (long)KV_ * HD_ * D_);
    cvt(wo, wob, (long)D_ * D_);

    // fused QKV projection -> bf16
    gemm_bt_lds<__hip_bfloat16><<<dim3(NCAT / 128, T / 128), 256, 0, stream>>>(
        (const short*)xb, (const short*)wcat, qkvb, T, NCAT, D_);

    // QK-norm + RoPE -> bf16 (packed); V -> transposed bf16
    {
        int nvq = T * H_ * 2;
        norm_rope_kernel<<<(nvq * 64 + 255) / 256, 256, 0, stream>>>(
            qkvb, qb16, freqs, qnw, nvq, H_, NCAT, 0);
        int nvk = T * KV_ * 2;
        norm_rope_kernel<<<(nvk * 64 + 255) / 256, 256, 0, stream>>>(
            qkvb, kb16, freqs, knw, nvk, KV_, NCAT, 2 * H_ * HD_);
        v_transpose_kernel<<<dim3(S_ / 64, KV_, B_), 256, 0, stream>>>(
            (const short*)qkvb, (short*)vT);
    }

    // differential causal attention
    attn_kernel<<<dim3(S_ / 64, H_, B_), 256, 0, stream>>>(
        (const short*)qb16, (const short*)kb16, (const short*)vT, aob, lam);

    // output projection -> f32
    gemm_bt_lds<float><<<dim3(D_ / 128, T / 128), 256, 0, stream>>>(
        (const short*)aob, (const short*)wob, out, T, D_, D_);
}

// Round 6
// 244.622 us; speedup vs baseline: 1.0281x; 1.0281x over previous
//
#include <hip/hip_runtime.h>
#include <hip/hip_bf16.h>

#define B_ 2
#define S_ 2048
#define D_ 1024
#define H_ 16
#define KV_ 4
#define HD_ 64
#define G_ (H_ / KV_)
#define NCAT 2816          // 2*H*HD + 2*KV*HD + KV*HD
#define VOFF 2560          // col offset of V block in fused QKV output

typedef __attribute__((ext_vector_type(8))) short short8;
typedef __attribute__((ext_vector_type(4))) short short4v;
typedef __attribute__((ext_vector_type(4))) float floatx4;

using gvoid_p = const __attribute__((address_space(1))) void*;
using lvoid_p = __attribute__((address_space(3))) void*;

__device__ inline void gload_lds16(const short* g, short* l) {
    __builtin_amdgcn_global_load_lds((gvoid_p)(const void*)g, (lvoid_p)(void*)l, 16, 0, 0);
}

__device__ inline int cvt_pk_bf16(float lo, float hi) {
    int r;
    asm volatile("v_cvt_pk_bf16_f32 %0, %1, %2" : "=v"(r) : "v"(lo), "v"(hi));
    return r;
}

// ---------------- fp32 -> bf16 convert ----------------
__global__ void cvt_bf16_kernel(const float* __restrict__ in,
                                __hip_bfloat16* __restrict__ out, int n) {
    int i = blockIdx.x * blockDim.x + threadIdx.x;
    if (i < n) out[i] = __float2bfloat16(in[i]);
}

// ---------------- NT GEMM, LDS double-buffered with counted vmcnt (T3 2-phase) ----------
template <typename OutT>
__global__ __launch_bounds__(256) void gemm_bt_lds(const short* __restrict__ A,
                                                   const short* __restrict__ Bm,
                                                   OutT* __restrict__ C,
                                                   int M, int N, int K) {
    __shared__ __align__(16) short As[2][128 * 32];
    __shared__ __align__(16) short Bs[2][128 * 32];
    int tid = threadIdx.x;
    int wid = tid >> 6, lane = tid & 63;
    int wr = wid >> 1, wc = wid & 1;
    int r = lane & 15, kq = lane >> 4;
    long m0 = (long)blockIdx.y * 128;
    long n0 = (long)blockIdx.x * 128;

    const short* gA0 = A + (m0 + (tid >> 2)) * (long)K + (tid & 3) * 8;
    const short* gA1 = A + (m0 + 64 + (tid >> 2)) * (long)K + (tid & 3) * 8;
    const short* gB0 = Bm + (n0 + (tid >> 2)) * (long)K + (tid & 3) * 8;
    const short* gB1 = Bm + (n0 + 64 + (tid >> 2)) * (long)K + (tid & 3) * 8;

    auto stage = [&](int buf, int k0) {
        gload_lds16(gA0 + k0, &As[buf][wid * 512]);
        gload_lds16(gA1 + k0, &As[buf][2048 + wid * 512]);
        gload_lds16(gB0 + k0, &Bs[buf][wid * 512]);
        gload_lds16(gB1 + k0, &Bs[buf][2048 + wid * 512]);
    };

    floatx4 acc[4][4];
#pragma unroll
    for (int i = 0; i < 4; ++i)
#pragma unroll
        for (int j = 0; j < 4; ++j) acc[i][j] = {0.f, 0.f, 0.f, 0.f};

    int nt = K >> 5;
    stage(0, 0);
    for (int t = 0; t < nt; ++t) {
        int cur = t & 1;
        __builtin_amdgcn_s_barrier();
        if (t + 1 < nt) {
            stage(cur ^ 1, (t + 1) << 5);
            asm volatile("s_waitcnt vmcnt(4)" ::: "memory");
        } else {
            asm volatile("s_waitcnt vmcnt(0)" ::: "memory");
        }
        __builtin_amdgcn_sched_barrier(0);
        __builtin_amdgcn_s_barrier();
        short8 a[4], b[4];
#pragma unroll
        for (int mi = 0; mi < 4; ++mi)
            a[mi] = *(const short8*)&As[cur][(wr * 64 + mi * 16 + r) * 32 + kq * 8];
#pragma unroll
        for (int ni = 0; ni < 4; ++ni)
            b[ni] = *(const short8*)&Bs[cur][(wc * 64 + ni * 16 + r) * 32 + kq * 8];
#pragma unroll
        for (int mi = 0; mi < 4; ++mi)
#pragma unroll
            for (int ni = 0; ni < 4; ++ni)
                acc[mi][ni] = __builtin_amdgcn_mfma_f32_16x16x32_bf16(
                    a[mi], b[ni], acc[mi][ni], 0, 0, 0);
    }
    int col_l = lane & 15, row_l = (lane >> 4) * 4;
#pragma unroll
    for (int mi = 0; mi < 4; ++mi)
#pragma unroll
        for (int ni = 0; ni < 4; ++ni) {
            long col = n0 + wc * 64 + ni * 16 + col_l;
            long row0 = m0 + wr * 64 + mi * 16 + row_l;
#pragma unroll
            for (int j = 0; j < 4; ++j) {
                float v = acc[mi][ni][j];
                if constexpr (__is_same(OutT, float))
                    C[(row0 + j) * N + col] = v;
                else
                    C[(row0 + j) * N + col] = __float2bfloat16(v);
            }
        }
}

// ---------------- RMSNorm (per-64) + RoPE, strided bf16 in -> packed bf16 out ----------------
__global__ void norm_rope_kernel(const __hip_bfloat16* __restrict__ buf,
                                 __hip_bfloat16* __restrict__ outb,
                                 const float* __restrict__ freqs,
                                 const float* __restrict__ w, int nvec, int nh,
                                 int tstride, int colbase) {
    int gt = blockIdx.x * blockDim.x + threadIdx.x;
    int gw = gt >> 6;
    int lane = gt & 63;
    if (gw >= nvec) return;
    int t = gw / (nh * 2);
    int rem = gw - t * (nh * 2);
    int s = t & (S_ - 1);
    const __hip_bfloat16* v = buf + (long)t * tstride + colbase + rem * 64;
    float x = __bfloat162float(v[lane]);
    float ss = x * x;
#pragma unroll
    for (int off = 32; off; off >>= 1) ss += __shfl_xor(ss, off);
    float r = rsqrtf(ss * (1.f / 64.f) + 1e-6f);
    x = x * r * w[lane];
    int i = lane >> 1;
    float c  = freqs[(s * (HD_ / 2) + i) * 2];
    float sn = freqs[(s * (HD_ / 2) + i) * 2 + 1];
    float p = __shfl_xor(x, 1);
    float y = (lane & 1) ? fmaf(p, sn, x * c) : fmaf(x, c, -(p * sn));
    outb[(long)gw * 64 + lane] = __float2bfloat16(y);
}

// ---------------- V transpose: qkvb bf16 [t][NCAT] -> vT bf16 [b][kv][d][s] ----------------
__global__ __launch_bounds__(256) void v_transpose_kernel(const short* __restrict__ src,
                                                          short* __restrict__ dst) {
    __shared__ short ls[64][72];
    int s0 = blockIdx.x * 64;
    int kv = blockIdx.y, b = blockIdx.z;
    int tid = threadIdx.x;
    const short* base = src + ((long)(b * S_ + s0)) * NCAT + VOFF + kv * 64;
    {
        int rr = tid >> 2, cc = (tid & 3) * 16;
        *(short8*)&ls[rr][cc]     = *(const short8*)(base + (long)rr * NCAT + cc);
        *(short8*)&ls[rr][cc + 8] = *(const short8*)(base + (long)rr * NCAT + cc + 8);
    }
    __syncthreads();
    short* ob = dst + ((long)(b * KV_ + kv) * 64) * S_ + s0;
    {
        int d = tid >> 2, sl = (tid & 3) * 16;
        short8 o0, o1;
#pragma unroll
        for (int e = 0; e < 8; ++e) { o0[e] = ls[sl + e][d]; o1[e] = ls[sl + 8 + e][d]; }
        *(short8*)(ob + (long)d * S_ + sl)     = o0;
        *(short8*)(ob + (long)d * S_ + sl + 8) = o1;
    }
}

// ---------------- differential causal attention (MFMA flash, k-split uniform blocks) ------
// Fixed-offset softmax => (acc,l) are LINEAR in k-tiles => k-range splittable across
// blocks, merged by addition. Pairing: pair p = (qtA=p, qtB=31-p) = 33 tile-units,
// split 17/16 across blocks e=0/e=1. e=0: qtA fully (direct output) + k-prefix of qtB
// (partial slot 0). e=1: k-suffix of qtB incl diagonal (partial slot 1).
// 1024 uniform blocks -> 4 blocks/CU resident, no makespan tail.
// Swapped QK^T: lane (r,kq) holds P[q=r][k=16nt+4kq+j] = 16x16x16 A-frag layout.
// Row-sums via ones-column MFMA (lands as accl[j] = L[q=kq*4+j], matching epilogue).
__global__ __launch_bounds__(256) void attn_kernel(const short* __restrict__ qb,
                                                   const short* __restrict__ kbuf,
                                                   const short* __restrict__ vtb,
                                                   __hip_bfloat16* __restrict__ ob,
                                                   float* __restrict__ part,
                                                   float* __restrict__ lpart,
                                                   const float* __restrict__ lam_p) {
    __shared__ __align__(16) short k1s[64][72];
    __shared__ __align__(16) short k2s[64][72];
    __shared__ __align__(16) short vts[64][76];

    int tid = threadIdx.x, w = tid >> 6, lane = tid & 63;
    int b = blockIdx.z, h = blockIdx.y, kv = h / G_;
    int p = (int)blockIdx.x >> 1, e = (int)blockIdx.x & 1;
    int qtA = p, qtB = 31 - p;
    int splitB = 16 - p;               // e=0 covers k-tiles [0,splitB) of qtB
    int r = lane & 15, kq = lane >> 4;
    float lam = lam_p[0];

    floatx4 acc[2][4];
    floatx4 accl[2];
    short8 qa[2][2];

    const short* vbase = vtb + (long)(b * KV_ + kv) * 64 * S_;
    const float c1 = 0.18033688f, c2 = 6.40607e-5f, c3 = 4.9243e-9f, zoff = -17.3123405f;
    const short one_bf = (short)0x3F80;
    short4v ones4 = {one_bf, one_bf, one_bf, one_bf};

    auto reset_acc = [&]() {
#pragma unroll
        for (int m = 0; m < 2; ++m) {
            accl[m] = {0.f, 0.f, 0.f, 0.f};
#pragma unroll
            for (int dt = 0; dt < 4; ++dt) acc[m][dt] = {0.f, 0.f, 0.f, 0.f};
        }
    };
    auto load_q = [&](int q0) {
        const short* qrow = qb + ((long)(b * S_ + q0 + r) * H_ + h) * 128;
        qa[0][0] = *(const short8*)(qrow + kq * 8);
        qa[0][1] = *(const short8*)(qrow + 32 + kq * 8);
        qa[1][0] = *(const short8*)(qrow + 64 + kq * 8);
        qa[1][1] = *(const short8*)(qrow + 96 + kq * 8);
    };
    auto stage = [&](int kb) {
#pragma unroll
        for (int c = tid; c < 1024; c += 256) {
            int rr = c >> 4, cc = c & 15;
            short8 val = *(const short8*)(kbuf +
                ((long)(b * S_ + kb + rr) * KV_ + kv) * 128 + cc * 8);
            if (cc < 8) *(short8*)&k1s[rr][cc * 8] = val;
            else        *(short8*)&k2s[rr][(cc - 8) * 8] = val;
        }
#pragma unroll
        for (int c = tid; c < 512; c += 256) {
            int rr = c >> 3, cc = c & 7;
            *(short8*)&vts[rr][cc * 8] =
                *(const short8*)(vbase + (long)rr * S_ + kb + cc * 8);
        }
    };
    auto tile_compute = [&](int kb, int q0, bool domask) {
#pragma unroll
        for (int m = 0; m < 2; ++m) {
            const short (*ks)[72] = m ? k2s : k1s;
            floatx4 sacc[4];
#pragma unroll
            for (int nt = 0; nt < 4; ++nt) {
                sacc[nt] = {0.f, 0.f, 0.f, 0.f};
                short8 a0 = *(const short8*)&ks[nt * 16 + r][kq * 8];
                short8 a1 = *(const short8*)&ks[nt * 16 + r][32 + kq * 8];
                sacc[nt] = __builtin_amdgcn_mfma_f32_16x16x32_bf16(a0, qa[m][0], sacc[nt], 0, 0, 0);
                sacc[nt] = __builtin_amdgcn_mfma_f32_16x16x32_bf16(a1, qa[m][1], sacc[nt], 0, 0, 0);
            }
            short4v pa[4];
#pragma unroll
            for (int nt = 0; nt < 4; ++nt) {
                float pv[4];
#pragma unroll
                for (int j = 0; j < 4; ++j) {
                    float t = sacc[nt][j] * c1;
                    float t2 = t * t;
                    float u = fmaf(c3, t2, -c2);
                    float wv = fmaf(u, t2, 1.0f);
                    float z = fmaf(t, wv, zoff);
                    pv[j] = __builtin_amdgcn_exp2f(z);
                    if (domask && (kb + nt * 16 + kq * 4 + j > q0 + r)) pv[j] = 0.f;
                }
                int lo = cvt_pk_bf16(pv[0], pv[1]);
                int hi = cvt_pk_bf16(pv[2], pv[3]);
                pa[nt][0] = (short)(lo & 0xffff);
                pa[nt][1] = (short)((unsigned)lo >> 16);
                pa[nt][2] = (short)(hi & 0xffff);
                pa[nt][3] = (short)((unsigned)hi >> 16);
            }
#pragma unroll
            for (int dt = 0; dt < 4; ++dt) {
#pragma unroll
                for (int nt = 0; nt < 4; ++nt) {
                    short4v vb = *(const short4v*)&vts[dt * 16 + r][16 * nt + 4 * kq];
                    acc[m][dt] = __builtin_amdgcn_mfma_f32_16x16x16bf16_1k(
                        pa[nt], vb, acc[m][dt], 0, 0, 0);
                }
            }
#pragma unroll
            for (int nt = 0; nt < 4; ++nt)
                accl[m] = __builtin_amdgcn_mfma_f32_16x16x16bf16_1k(
                    pa[nt], ones4, accl[m], 0, 0, 0);
        }
    };
    auto run = [&](int qt, int ki0, int ki1, bool diag) {
        int q0 = qt * 64 + w * 16;
        load_q(q0);
        reset_acc();
        for (int ki = ki0; ki < ki1; ++ki) {
            int kb = ki * 64;
            __syncthreads();
            stage(kb);
            __syncthreads();
            tile_compute(kb, q0, diag && (ki == qt));
        }
    };

    if (e == 0) {
        // segment 1: qtA fully, direct output
        run(qtA, 0, qtA + 1, true);
        {
            int q0 = qtA * 64 + w * 16;
#pragma unroll
            for (int j = 0; j < 4; ++j) {
                float i1 = 1.f / accl[0][j];
                float i2 = lam / accl[1][j];
                int qr = q0 + kq * 4 + j;
                __hip_bfloat16* orow = ob + ((long)(b * S_ + qr) * H_ + h) * 64;
#pragma unroll
                for (int dt = 0; dt < 4; ++dt) {
                    float val = acc[0][dt][j] * i1 - acc[1][dt][j] * i2;
                    orow[dt * 16 + r] = __float2bfloat16(val);
                }
            }
        }
        // segment 2: k-prefix of qtB -> partial slot 0
        run(qtB, 0, splitB, false);
    } else {
        // k-suffix of qtB (incl diagonal) -> partial slot 1
        run(qtB, splitB, 32 - p, true);
    }

    // write partial (both e=0 seg2 and e=1): slot = (b*H+h)*16 + (qtB-16), half = e
    {
        long slot = (long)(b * H_ + h) * 16 + (qtB - 16);
        long base = ((slot * 2 + e) * 2) * 4096L;
        int qloc = w * 16 + kq * 4;
#pragma unroll
        for (int m = 0; m < 2; ++m)
#pragma unroll
            for (int dt = 0; dt < 4; ++dt)
#pragma unroll
                for (int j = 0; j < 4; ++j)
                    part[base + m * 4096L + (qloc + j) * 64 + dt * 16 + r] = acc[m][dt][j];
        if (r == 0) {
#pragma unroll
            for (int m = 0; m < 2; ++m)
#pragma unroll
                for (int j = 0; j < 4; ++j)
                    lpart[((slot * 2 + e) * 2 + m) * 64 + qloc + j] = accl[m][j];
        }
    }
}

// ---------------- merge partials for qt in [16,32): out = sum/sum - lam*sum/sum ----------
__global__ __launch_bounds__(256) void attn_merge_kernel(const float* __restrict__ part,
                                                         const float* __restrict__ lpart,
                                                         __hip_bfloat16* __restrict__ ob,
                                                         const float* __restrict__ lam_p) {
    long sid = blockIdx.x;               // (b*H+h)*16 + (qt-16)
    int t16 = sid & 15;
    int h = (sid >> 4) & (H_ - 1);
    int b = (int)(sid >> 8);
    int qt = 16 + t16;
    float lam = lam_p[0];
    const float* p0 = part + sid * 4 * 4096L;          // half 0, m at +m*4096
    const float* p1 = part + (sid * 4 + 2) * 4096L;    // half 1
    const float* l0 = lpart + sid * 4 * 64L;
    const float* l1 = lpart + (sid * 4 + 2) * 64L;
    int tid = threadIdx.x;
#pragma unroll
    for (int i = 0; i < 16; ++i) {
        int idx = i * 256 + tid;
        int q = idx >> 6, d = idx & 63;
        float a1 = p0[q * 64 + d] + p1[q * 64 + d];
        float a2 = p0[4096 + q * 64 + d] + p1[4096 + q * 64 + d];
        float L1 = l0[q] + l1[q];
        float L2 = l0[64 + q] + l1[64 + q];
        float val = a1 / L1 - lam * (a2 / L2);
        ob[((long)(b * S_ + qt * 64 + q) * H_ + h) * 64 + d] = __float2bfloat16(val);
    }
}

// ---------------- launch ----------------
extern "C" void kernel_launch(void* const* d_in, const int* in_sizes, int n_in,
                              void* d_out, int out_size, void* d_ws, size_t ws_size,
                              hipStream_t stream) {
    const float* x     = (const float*)d_in[0];
    const float* freqs = (const float*)d_in[1];
    const float* wq    = (const float*)d_in[2];
    const float* wk    = (const float*)d_in[3];
    const float* wv    = (const float*)d_in[4];
    const float* wo    = (const float*)d_in[5];
    const float* qnw   = (const float*)d_in[6];
    const float* knw   = (const float*)d_in[7];
    const float* lam   = (const float*)d_in[8];
    float* out = (float*)d_out;

    const int T = B_ * S_;
    char* ws = (char*)d_ws;
    size_t off = 0;
    auto alloc = [&](size_t bytes) {
        void* p = ws + off;
        off += (bytes + 255) & ~(size_t)255;
        return p;
    };
    __hip_bfloat16* xb   = (__hip_bfloat16*)alloc((size_t)T * D_ * 2);
    __hip_bfloat16* wcat = (__hip_bfloat16*)alloc((size_t)NCAT * D_ * 2);
    __hip_bfloat16* wob  = (__hip_bfloat16*)alloc((size_t)D_ * D_ * 2);
    __hip_bfloat16* qkvb = (__hip_bfloat16*)alloc((size_t)T * NCAT * 2);
    __hip_bfloat16* qb16 = (__hip_bfloat16*)alloc((size_t)T * 2 * H_ * HD_ * 2);
    __hip_bfloat16* kb16 = (__hip_bfloat16*)alloc((size_t)T * 2 * KV_ * HD_ * 2);
    __hip_bfloat16* vT   = (__hip_bfloat16*)alloc((size_t)B_ * KV_ * HD_ * S_ * 2);
    float* part  = (float*)alloc((size_t)512 * 2 * 2 * 4096 * 4);
    float* lpart = (float*)alloc((size_t)512 * 2 * 2 * 64 * 4);
    __hip_bfloat16* aob  = xb;   // xb dead after QKV GEMM; same size

    auto cvt = [&](const float* src, __hip_bfloat16* dst, long n) {
        cvt_bf16_kernel<<<(n + 255) / 256, 256, 0, stream>>>(src, dst, (int)n);
    };
    cvt(x, xb, (long)T * D_);
    cvt(wq, wcat, (long)2 * H_ * HD_ * D_);
    cvt(wk, wcat + (size_t)2 * H_ * HD_ * D_, (long)2 * KV_ * HD_ * D_);
    cvt(wv, wcat + (size_t)(2 * H_ * HD_ + 2 * KV_ * HD_) * D_, (long)KV_ * HD_ * D_);
    cvt(wo, wob, (long)D_ * D_);

    // fused QKV projection -> bf16
    gemm_bt_lds<__hip_bfloat16><<<dim3(NCAT / 128, T / 128), 256, 0, stream>>>(
        (const short*)xb, (const short*)wcat, qkvb, T, NCAT, D_);

    // QK-norm + RoPE -> bf16 (packed); V -> transposed bf16
    {
        int nvq = T * H_ * 2;
        norm_rope_kernel<<<(nvq * 64 + 255) / 256, 256, 0, stream>>>(
            qkvb, qb16, freqs, qnw, nvq, H_, NCAT, 0);
        int nvk = T * KV_ * 2;
        norm_rope_kernel<<<(nvk * 64 + 255) / 256, 256, 0, stream>>>(
            qkvb, kb16, freqs, knw, nvk, KV_, NCAT, 2 * H_ * HD_);
        v_transpose_kernel<<<dim3(S_ / 64, KV_, B_), 256, 0, stream>>>(
            (const short*)qkvb, (short*)vT);
    }

    // differential causal attention: uniform k-split blocks + merge
    attn_kernel<<<dim3(32, H_, B_), 256, 0, stream>>>(
        (const short*)qb16, (const short*)kb16, (const short*)vT, aob, part, lpart, lam);
    attn_merge_kernel<<<512, 256, 0, stream>>>(part, lpart, aob, lam);

    // output projection -> f32
    gemm_bt_lds<float><<<dim3(D_ / 128, T / 128), 256, 0, stream>>>(
        (const short*)aob, (const short*)wob, out, T, D_, D_);
}

// Round 7
// 192.545 us; speedup vs baseline: 1.3061x; 1.2705x over previous
//
#include <hip/hip_runtime.h>
#include <hip/hip_bf16.h>

#define B_ 2
#define S_ 2048
#define D_ 1024
#define H_ 16
#define KV_ 4
#define HD_ 64
#define G_ (H_ / KV_)
#define NCAT 2816          // 2*H*HD + 2*KV*HD + KV*HD
#define VOFF 2560          // col offset of V block in fused QKV output

typedef __attribute__((ext_vector_type(8))) short short8;
typedef __attribute__((ext_vector_type(4))) short short4v;
typedef __attribute__((ext_vector_type(2))) int int2v;
typedef __attribute__((ext_vector_type(4))) float floatx4;

using gvoid_p = const __attribute__((address_space(1))) void*;
using lvoid_p = __attribute__((address_space(3))) void*;

__device__ inline void gload_lds16(const short* g, short* l) {
    __builtin_amdgcn_global_load_lds((gvoid_p)(const void*)g, (lvoid_p)(void*)l, 16, 0, 0);
}

__device__ inline int cvt_pk_bf16(float lo, float hi) {
    int r;
    asm volatile("v_cvt_pk_bf16_f32 %0, %1, %2" : "=v"(r) : "v"(lo), "v"(hi));
    return r;
}

// ---------------- fp32 -> bf16 convert ----------------
__global__ void cvt_bf16_kernel(const float* __restrict__ in,
                                __hip_bfloat16* __restrict__ out, int n) {
    int i = blockIdx.x * blockDim.x + threadIdx.x;
    if (i < n) out[i] = __float2bfloat16(in[i]);
}

// ---------------- NT GEMM, LDS double-buffered with counted vmcnt ----------
template <typename OutT>
__global__ __launch_bounds__(256) void gemm_bt_lds(const short* __restrict__ A,
                                                   const short* __restrict__ Bm,
                                                   OutT* __restrict__ C,
                                                   int M, int N, int K) {
    __shared__ __align__(16) short As[2][128 * 32];
    __shared__ __align__(16) short Bs[2][128 * 32];
    int tid = threadIdx.x;
    int wid = tid >> 6, lane = tid & 63;
    int wr = wid >> 1, wc = wid & 1;
    int r = lane & 15, kq = lane >> 4;
    long m0 = (long)blockIdx.y * 128;
    long n0 = (long)blockIdx.x * 128;

    const short* gA0 = A + (m0 + (tid >> 2)) * (long)K + (tid & 3) * 8;
    const short* gA1 = A + (m0 + 64 + (tid >> 2)) * (long)K + (tid & 3) * 8;
    const short* gB0 = Bm + (n0 + (tid >> 2)) * (long)K + (tid & 3) * 8;
    const short* gB1 = Bm + (n0 + 64 + (tid >> 2)) * (long)K + (tid & 3) * 8;

    auto stage = [&](int buf, int k0) {
        gload_lds16(gA0 + k0, &As[buf][wid * 512]);
        gload_lds16(gA1 + k0, &As[buf][2048 + wid * 512]);
        gload_lds16(gB0 + k0, &Bs[buf][wid * 512]);
        gload_lds16(gB1 + k0, &Bs[buf][2048 + wid * 512]);
    };

    floatx4 acc[4][4];
#pragma unroll
    for (int i = 0; i < 4; ++i)
#pragma unroll
        for (int j = 0; j < 4; ++j) acc[i][j] = {0.f, 0.f, 0.f, 0.f};

    int nt = K >> 5;
    stage(0, 0);
    for (int t = 0; t < nt; ++t) {
        int cur = t & 1;
        __builtin_amdgcn_s_barrier();
        if (t + 1 < nt) {
            stage(cur ^ 1, (t + 1) << 5);
            asm volatile("s_waitcnt vmcnt(4)" ::: "memory");
        } else {
            asm volatile("s_waitcnt vmcnt(0)" ::: "memory");
        }
        __builtin_amdgcn_sched_barrier(0);
        __builtin_amdgcn_s_barrier();
        short8 a[4], b[4];
#pragma unroll
        for (int mi = 0; mi < 4; ++mi)
            a[mi] = *(const short8*)&As[cur][(wr * 64 + mi * 16 + r) * 32 + kq * 8];
#pragma unroll
        for (int ni = 0; ni < 4; ++ni)
            b[ni] = *(const short8*)&Bs[cur][(wc * 64 + ni * 16 + r) * 32 + kq * 8];
#pragma unroll
        for (int mi = 0; mi < 4; ++mi)
#pragma unroll
            for (int ni = 0; ni < 4; ++ni)
                acc[mi][ni] = __builtin_amdgcn_mfma_f32_16x16x32_bf16(
                    a[mi], b[ni], acc[mi][ni], 0, 0, 0);
    }
    int col_l = lane & 15, row_l = (lane >> 4) * 4;
#pragma unroll
    for (int mi = 0; mi < 4; ++mi)
#pragma unroll
        for (int ni = 0; ni < 4; ++ni) {
            long col = n0 + wc * 64 + ni * 16 + col_l;
            long row0 = m0 + wr * 64 + mi * 16 + row_l;
#pragma unroll
            for (int j = 0; j < 4; ++j) {
                float v = acc[mi][ni][j];
                if constexpr (__is_same(OutT, float))
                    C[(row0 + j) * N + col] = v;
                else
                    C[(row0 + j) * N + col] = __float2bfloat16(v);
            }
        }
}

// ---------------- RMSNorm (per-64) + RoPE, strided bf16 in -> packed bf16 out ----------------
__global__ void norm_rope_kernel(const __hip_bfloat16* __restrict__ buf,
                                 __hip_bfloat16* __restrict__ outb,
                                 const float* __restrict__ freqs,
                                 const float* __restrict__ w, int nvec, int nh,
                                 int tstride, int colbase) {
    int gt = blockIdx.x * blockDim.x + threadIdx.x;
    int gw = gt >> 6;
    int lane = gt & 63;
    if (gw >= nvec) return;
    int t = gw / (nh * 2);
    int rem = gw - t * (nh * 2);
    int s = t & (S_ - 1);
    const __hip_bfloat16* v = buf + (long)t * tstride + colbase + rem * 64;
    float x = __bfloat162float(v[lane]);
    float ss = x * x;
#pragma unroll
    for (int off = 32; off; off >>= 1) ss += __shfl_xor(ss, off);
    float r = rsqrtf(ss * (1.f / 64.f) + 1e-6f);
    x = x * r * w[lane];
    int i = lane >> 1;
    float c  = freqs[(s * (HD_ / 2) + i) * 2];
    float sn = freqs[(s * (HD_ / 2) + i) * 2 + 1];
    float p = __shfl_xor(x, 1);
    float y = (lane & 1) ? fmaf(p, sn, x * c) : fmaf(x, c, -(p * sn));
    outb[(long)gw * 64 + lane] = __float2bfloat16(y);
}

// ---------------- V transpose: qkvb bf16 [t][NCAT] -> vT bf16 [b][kv][d][s] ----------------
__global__ __launch_bounds__(256) void v_transpose_kernel(const short* __restrict__ src,
                                                          short* __restrict__ dst) {
    __shared__ short ls[64][72];
    int s0 = blockIdx.x * 64;
    int kv = blockIdx.y, b = blockIdx.z;
    int tid = threadIdx.x;
    const short* base = src + ((long)(b * S_ + s0)) * NCAT + VOFF + kv * 64;
    {
        int rr = tid >> 2, cc = (tid & 3) * 16;
        *(short8*)&ls[rr][cc]     = *(const short8*)(base + (long)rr * NCAT + cc);
        *(short8*)&ls[rr][cc + 8] = *(const short8*)(base + (long)rr * NCAT + cc + 8);
    }
    __syncthreads();
    short* ob = dst + ((long)(b * KV_ + kv) * 64) * S_ + s0;
    {
        int d = tid >> 2, sl = (tid & 3) * 16;
        short8 o0, o1;
#pragma unroll
        for (int e = 0; e < 8; ++e) { o0[e] = ls[sl + e][d]; o1[e] = ls[sl + 8 + e][d]; }
        *(short8*)(ob + (long)d * S_ + sl)     = o0;
        *(short8*)(ob + (long)d * S_ + sl + 8) = o1;
    }
}

// ---------------- differential causal attention ----------------
// KVBLK=32. K: global_load_lds double-buffer, XOR-swizzled via global SOURCE
// (linear LDS dest, same involution on read — m173 pattern). V: reg-staged
// single buffer [64][40] (16B-aligned rows, 2-way-free reads). Depth-1
// prefetch with counted vmcnt; raw barriers (loads stay in flight).
// k-split pairing as r6: pair p=(qtA=p, qtB=31-p), 33 32-k-tiles per block.
__global__ __launch_bounds__(256, 4) void attn_kernel(const short* __restrict__ qb,
                                                      const short* __restrict__ kbuf,
                                                      const short* __restrict__ vtb,
                                                      __hip_bfloat16* __restrict__ ob,
                                                      float* __restrict__ part,
                                                      float* __restrict__ lpart,
                                                      const float* __restrict__ lam_p) {
    __shared__ __align__(16) short Ks[2][32][128];
    __shared__ __align__(16) short Vt[64][40];

    int tid = threadIdx.x, w = tid >> 6, lane = tid & 63;
    int b = blockIdx.z, h = blockIdx.y, kv = h / G_;
    int p = (int)blockIdx.x >> 1, e = (int)blockIdx.x & 1;
    int qtA = p, qtB = 31 - p;
    int r = lane & 15, kq = lane >> 4;
    float lam = lam_p[0];

    floatx4 acc[2][4];
    floatx4 accl[2];
    short8 qa[2][2];

    const short* vbase = vtb + (long)(b * KV_ + kv) * 64 * S_;
    const float cc1 = 0.18033688f, cc2 = 6.40607e-5f, cc3 = 4.9243e-9f, zoff = -17.3123405f;
    const short one_bf = (short)0x3F80;
    short4v ones4 = {one_bf, one_bf, one_bf, one_bf};

    // K staging geometry: 512 chunks of 16B per tile, 2 per thread.
    // chunk c -> LDS row c>>4, 16B-slot c&15 (linear dest);
    // global source col pre-swizzled: slot' = (c&15) ^ (row&7).
    int ch0 = tid, ch1 = tid + 256;
    int krow0 = ch0 >> 4, kcs0 = ((ch0 & 15) ^ (krow0 & 7)) * 8;
    int krow1 = ch1 >> 4, kcs1 = ((ch1 & 15) ^ (krow1 & 7)) * 8;
    const short* kgb = kbuf + ((long)b * S_ * KV_ + kv) * 128;
    int vd = tid >> 2, vch = tid & 3;

    auto issueK = [&](int buf, int ki) {
        long rb = (long)(ki * 32) * (KV_ * 128);
        gload_lds16(kgb + rb + (long)krow0 * (KV_ * 128) + kcs0, &Ks[buf][0][0] + w * 512);
        gload_lds16(kgb + rb + (long)krow1 * (KV_ * 128) + kcs1, &Ks[buf][0][0] + 2048 + w * 512);
    };
    auto loadV = [&](int kb) {
        return *(const short8*)(vbase + (long)vd * S_ + kb + vch * 8);
    };

    auto reset_acc = [&]() {
#pragma unroll
        for (int m = 0; m < 2; ++m) {
            accl[m] = {0.f, 0.f, 0.f, 0.f};
#pragma unroll
            for (int dt = 0; dt < 4; ++dt) acc[m][dt] = {0.f, 0.f, 0.f, 0.f};
        }
    };
    auto load_q = [&](int q0) {
        const short* qrow = qb + ((long)(b * S_ + q0 + r) * H_ + h) * 128;
        qa[0][0] = *(const short8*)(qrow + kq * 8);
        qa[0][1] = *(const short8*)(qrow + 32 + kq * 8);
        qa[1][0] = *(const short8*)(qrow + 64 + kq * 8);
        qa[1][1] = *(const short8*)(qrow + 96 + kq * 8);
    };

    auto tile_compute = [&](int cur, int kb, int q0, bool domask) {
#pragma unroll
        for (int m = 0; m < 2; ++m) {
            floatx4 sacc[2];
#pragma unroll
            for (int nt = 0; nt < 2; ++nt) {
                sacc[nt] = {0.f, 0.f, 0.f, 0.f};
                const short* row = &Ks[cur][nt * 16 + r][0];
                short8 a0 = *(const short8*)(row + (((m * 8) + kq) ^ (r & 7)) * 8);
                short8 a1 = *(const short8*)(row + (((m * 8) + 4 + kq) ^ (r & 7)) * 8);
                sacc[nt] = __builtin_amdgcn_mfma_f32_16x16x32_bf16(a0, qa[m][0], sacc[nt], 0, 0, 0);
                sacc[nt] = __builtin_amdgcn_mfma_f32_16x16x32_bf16(a1, qa[m][1], sacc[nt], 0, 0, 0);
            }
            short4v pa[2];
#pragma unroll
            for (int nt = 0; nt < 2; ++nt) {
                float pv[4];
#pragma unroll
                for (int j = 0; j < 4; ++j) {
                    float t = sacc[nt][j] * cc1;
                    float t2 = t * t;
                    float u = fmaf(cc3, t2, -cc2);
                    float wv = fmaf(u, t2, 1.0f);
                    float z = fmaf(t, wv, zoff);
                    pv[j] = __builtin_amdgcn_exp2f(z);
                    if (domask && (kb + nt * 16 + kq * 4 + j > q0 + r)) pv[j] = 0.f;
                }
                int lo = cvt_pk_bf16(pv[0], pv[1]);
                int hi = cvt_pk_bf16(pv[2], pv[3]);
                pa[nt] = __builtin_bit_cast(short4v, int2v{lo, hi});
            }
#pragma unroll
            for (int dt = 0; dt < 4; ++dt) {
#pragma unroll
                for (int nt = 0; nt < 2; ++nt) {
                    short4v vb = *(const short4v*)&Vt[dt * 16 + r][nt * 16 + kq * 4];
                    acc[m][dt] = __builtin_amdgcn_mfma_f32_16x16x16bf16_1k(
                        pa[nt], vb, acc[m][dt], 0, 0, 0);
                }
            }
#pragma unroll
            for (int nt = 0; nt < 2; ++nt)
                accl[m] = __builtin_amdgcn_mfma_f32_16x16x16bf16_1k(
                    pa[nt], ones4, accl[m], 0, 0, 0);
        }
    };

    // run over 32-k-tiles [ki0, ki1) of q-tile qt
    auto run = [&](int qt, int ki0, int ki1, bool diag) {
        int q0 = qt * 64 + w * 16;
        load_q(q0);
        reset_acc();
        int nseg = ki1 - ki0;
        issueK(0, ki0);
        short8 rv = loadV(ki0 * 32), rvn;
        for (int ii = 0; ii < nseg; ++ii) {
            int ki = ki0 + ii, cur = ii & 1;
            bool pre = (ii + 1 < nseg);
            if (pre) {
                issueK(cur ^ 1, ki + 1);
                rvn = loadV((ki + 1) * 32);
                asm volatile("s_waitcnt vmcnt(3)" ::: "memory");
            } else {
                asm volatile("s_waitcnt vmcnt(0)" ::: "memory");
            }
            __builtin_amdgcn_sched_barrier(0);
            *(short8*)&Vt[vd][vch * 8] = rv;
            rv = rvn;
            asm volatile("s_waitcnt lgkmcnt(0)" ::: "memory");
            __builtin_amdgcn_sched_barrier(0);
            __builtin_amdgcn_s_barrier();
            tile_compute(cur, ki * 32, q0, diag && ((ki >> 1) == qt));
            __builtin_amdgcn_s_barrier();
        }
    };

    if (e == 0) {
        run(qtA, 0, 2 * qtA + 2, true);
        {
            int q0 = qtA * 64 + w * 16;
#pragma unroll
            for (int j = 0; j < 4; ++j) {
                float i1 = 1.f / accl[0][j];
                float i2 = lam / accl[1][j];
                int qr = q0 + kq * 4 + j;
                __hip_bfloat16* orow = ob + ((long)(b * S_ + qr) * H_ + h) * 64;
#pragma unroll
                for (int dt = 0; dt < 4; ++dt) {
                    float val = acc[0][dt][j] * i1 - acc[1][dt][j] * i2;
                    orow[dt * 16 + r] = __float2bfloat16(val);
                }
            }
        }
        run(qtB, 0, 31 - 2 * p, false);             // k-prefix of qtB
    } else {
        run(qtB, 31 - 2 * p, 64 - 2 * p, true);     // k-suffix incl diagonal
    }

    // write partial: slot = (b*H+h)*16 + (qtB-16), half = e
    {
        long slot = (long)(b * H_ + h) * 16 + (qtB - 16);
        long base = ((slot * 2 + e) * 2) * 4096L;
        int qloc = w * 16 + kq * 4;
#pragma unroll
        for (int m = 0; m < 2; ++m)
#pragma unroll
            for (int dt = 0; dt < 4; ++dt)
#pragma unroll
                for (int j = 0; j < 4; ++j)
                    part[base + m * 4096L + (qloc + j) * 64 + dt * 16 + r] = acc[m][dt][j];
        if (r == 0) {
#pragma unroll
            for (int m = 0; m < 2; ++m)
#pragma unroll
                for (int j = 0; j < 4; ++j)
                    lpart[((slot * 2 + e) * 2 + m) * 64 + qloc + j] = accl[m][j];
        }
    }
}

// ---------------- merge partials for qt in [16,32) ----------
__global__ __launch_bounds__(256) void attn_merge_kernel(const float* __restrict__ part,
                                                         const float* __restrict__ lpart,
                                                         __hip_bfloat16* __restrict__ ob,
                                                         const float* __restrict__ lam_p) {
    long sid = blockIdx.x;
    int t16 = sid & 15;
    int h = (sid >> 4) & (H_ - 1);
    int b = (int)(sid >> 8);
    int qt = 16 + t16;
    float lam = lam_p[0];
    const float* p0 = part + sid * 4 * 4096L;
    const float* p1 = part + (sid * 4 + 2) * 4096L;
    const float* l0 = lpart + sid * 4 * 64L;
    const float* l1 = lpart + (sid * 4 + 2) * 64L;
    int tid = threadIdx.x;
#pragma unroll
    for (int i = 0; i < 16; ++i) {
        int idx = i * 256 + tid;
        int q = idx >> 6, d = idx & 63;
        float a1 = p0[q * 64 + d] + p1[q * 64 + d];
        float a2 = p0[4096 + q * 64 + d] + p1[4096 + q * 64 + d];
        float L1 = l0[q] + l1[q];
        float L2 = l0[64 + q] + l1[64 + q];
        float val = a1 / L1 - lam * (a2 / L2);
        ob[((long)(b * S_ + qt * 64 + q) * H_ + h) * 64 + d] = __float2bfloat16(val);
    }
}

// ---------------- launch ----------------
extern "C" void kernel_launch(void* const* d_in, const int* in_sizes, int n_in,
                              void* d_out, int out_size, void* d_ws, size_t ws_size,
                              hipStream_t stream) {
    const float* x     = (const float*)d_in[0];
    const float* freqs = (const float*)d_in[1];
    const float* wq    = (const float*)d_in[2];
    const float* wk    = (const float*)d_in[3];
    const float* wv    = (const float*)d_in[4];
    const float* wo    = (const float*)d_in[5];
    const float* qnw   = (const float*)d_in[6];
    const float* knw   = (const float*)d_in[7];
    const float* lam   = (const float*)d_in[8];
    float* out = (float*)d_out;

    const int T = B_ * S_;
    char* ws = (char*)d_ws;
    size_t off = 0;
    auto alloc = [&](size_t bytes) {
        void* p = ws + off;
        off += (bytes + 255) & ~(size_t)255;
        return p;
    };
    __hip_bfloat16* xb   = (__hip_bfloat16*)alloc((size_t)T * D_ * 2);
    __hip_bfloat16* wcat = (__hip_bfloat16*)alloc((size_t)NCAT * D_ * 2);
    __hip_bfloat16* wob  = (__hip_bfloat16*)alloc((size_t)D_ * D_ * 2);
    __hip_bfloat16* qkvb = (__hip_bfloat16*)alloc((size_t)T * NCAT * 2);
    __hip_bfloat16* qb16 = (__hip_bfloat16*)alloc((size_t)T * 2 * H_ * HD_ * 2);
    __hip_bfloat16* kb16 = (__hip_bfloat16*)alloc((size_t)T * 2 * KV_ * HD_ * 2);
    __hip_bfloat16* vT   = (__hip_bfloat16*)alloc((size_t)B_ * KV_ * HD_ * S_ * 2);
    float* part  = (float*)alloc((size_t)512 * 2 * 2 * 4096 * 4);
    float* lpart = (float*)alloc((size_t)512 * 2 * 2 * 64 * 4);
    __hip_bfloat16* aob  = xb;

    auto cvt = [&](const float* src, __hip_bfloat16* dst, long n) {
        cvt_bf16_kernel<<<(n + 255) / 256, 256, 0, stream>>>(src, dst, (int)n);
    };
    cvt(x, xb, (long)T * D_);
    cvt(wq, wcat, (long)2 * H_ * HD_ * D_);
    cvt(wk, wcat + (size_t)2 * H_ * HD_ * D_, (long)2 * KV_ * HD_ * D_);
    cvt(wv, wcat + (size_t)(2 * H_ * HD_ + 2 * KV_ * HD_) * D_, (long)KV_ * HD_ * D_);
    cvt(wo, wob, (long)D_ * D_);

    gemm_bt_lds<__hip_bfloat16><<<dim3(NCAT / 128, T / 128), 256, 0, stream>>>(
        (const short*)xb, (const short*)wcat, qkvb, T, NCAT, D_);

    {
        int nvq = T * H_ * 2;
        norm_rope_kernel<<<(nvq * 64 + 255) / 256, 256, 0, stream>>>(
            qkvb, qb16, freqs, qnw, nvq, H_, NCAT, 0);
        int nvk = T * KV_ * 2;
        norm_rope_kernel<<<(nvk * 64 + 255) / 256, 256, 0, stream>>>(
            qkvb, kb16, freqs, knw, nvk, KV_, NCAT, 2 * H_ * HD_);
        v_transpose_kernel<<<dim3(S_ / 64, KV_, B_), 256, 0, stream>>>(
            (const short*)qkvb, (short*)vT);
    }

    attn_kernel<<<dim3(32, H_, B_), 256, 0, stream>>>(
        (const short*)qb16, (const short*)kb16, (const short*)vT, aob, part, lpart, lam);
    attn_merge_kernel<<<512, 256, 0, stream>>>(part, lpart, aob, lam);

    gemm_bt_lds<float><<<dim3(D_ / 128, T / 128), 256, 0, stream>>>(
        (const short*)aob, (const short*)wob, out, T, D_, D_);
}

// Round 8
// 174.145 us; speedup vs baseline: 1.4441x; 1.1057x over previous
//
#include <hip/hip_runtime.h>
#include <hip/hip_bf16.h>

#define B_ 2
#define S_ 2048
#define D_ 1024
#define H_ 16
#define KV_ 4
#define HD_ 64
#define G_ (H_ / KV_)
#define NCAT 2816          // 2*H*HD + 2*KV*HD + KV*HD
#define VOFF 2560          // col offset of V block in fused QKV output

typedef __attribute__((ext_vector_type(8))) short short8;
typedef __attribute__((ext_vector_type(4))) short short4v;
typedef __attribute__((ext_vector_type(2))) int int2v;
typedef __attribute__((ext_vector_type(4))) float floatx4;

using gvoid_p = const __attribute__((address_space(1))) void*;
using lvoid_p = __attribute__((address_space(3))) void*;

__device__ inline void gload_lds16(const short* g, short* l) {
    __builtin_amdgcn_global_load_lds((gvoid_p)(const void*)g, (lvoid_p)(void*)l, 16, 0, 0);
}

__device__ inline int cvt_pk_bf16(float lo, float hi) {
    int r;
    asm volatile("v_cvt_pk_bf16_f32 %0, %1, %2" : "=v"(r) : "v"(lo), "v"(hi));
    return r;
}

// ---------------- fused fp32 -> bf16 convert (5 segments, float4 vectorized) -------------
__global__ void cvt5_kernel(const float* s0, const float* s1, const float* s2,
                            const float* s3, const float* s4,
                            __hip_bfloat16* d0, __hip_bfloat16* d1, __hip_bfloat16* d2,
                            __hip_bfloat16* d3, __hip_bfloat16* d4,
                            int n0, int n1, int n2, int n3, int n4) {
    const float* s; __hip_bfloat16* d; int n;
    switch (blockIdx.y) {
        case 0: s = s0; d = d0; n = n0; break;
        case 1: s = s1; d = d1; n = n1; break;
        case 2: s = s2; d = d2; n = n2; break;
        case 3: s = s3; d = d3; n = n3; break;
        default: s = s4; d = d4; n = n4; break;
    }
    int nv = n >> 2;
    for (int i = blockIdx.x * blockDim.x + threadIdx.x; i < nv;
         i += gridDim.x * blockDim.x) {
        floatx4 v = ((const floatx4*)s)[i];
        short4v o;
#pragma unroll
        for (int e = 0; e < 4; ++e) {
            __hip_bfloat16 hh = __float2bfloat16(v[e]);
            o[e] = __builtin_bit_cast(short, hh);
        }
        ((short4v*)d)[i] = o;
    }
}

// ---------------- NT GEMM, LDS double-buffered, counted vmcnt, XCD-swizzled ----------
template <typename OutT>
__global__ __launch_bounds__(256) void gemm_bt_lds(const short* __restrict__ A,
                                                   const short* __restrict__ Bm,
                                                   OutT* __restrict__ C,
                                                   int M, int N, int K) {
    __shared__ __align__(16) short As[2][128 * 32];
    __shared__ __align__(16) short Bs[2][128 * 32];
    int tid = threadIdx.x;
    int wid = tid >> 6, lane = tid & 63;
    int wr = wid >> 1, wc = wid & 1;
    int r = lane & 15, kq = lane >> 4;

    // bijective XCD swizzle (m204; nwg % 8 == 0 for all our grids)
    int nwg = gridDim.x * gridDim.y;
    int orig = blockIdx.y * gridDim.x + blockIdx.x;
    int wg = (orig & 7) * (nwg >> 3) + (orig >> 3);
    int bx = wg % gridDim.x, by = wg / gridDim.x;

    long m0 = (long)by * 128;
    long n0 = (long)bx * 128;

    const short* gA0 = A + (m0 + (tid >> 2)) * (long)K + (tid & 3) * 8;
    const short* gA1 = A + (m0 + 64 + (tid >> 2)) * (long)K + (tid & 3) * 8;
    const short* gB0 = Bm + (n0 + (tid >> 2)) * (long)K + (tid & 3) * 8;
    const short* gB1 = Bm + (n0 + 64 + (tid >> 2)) * (long)K + (tid & 3) * 8;

    auto stage = [&](int buf, int k0) {
        gload_lds16(gA0 + k0, &As[buf][wid * 512]);
        gload_lds16(gA1 + k0, &As[buf][2048 + wid * 512]);
        gload_lds16(gB0 + k0, &Bs[buf][wid * 512]);
        gload_lds16(gB1 + k0, &Bs[buf][2048 + wid * 512]);
    };

    floatx4 acc[4][4];
#pragma unroll
    for (int i = 0; i < 4; ++i)
#pragma unroll
        for (int j = 0; j < 4; ++j) acc[i][j] = {0.f, 0.f, 0.f, 0.f};

    int nt = K >> 5;
    stage(0, 0);
    for (int t = 0; t < nt; ++t) {
        int cur = t & 1;
        __builtin_amdgcn_s_barrier();
        if (t + 1 < nt) {
            stage(cur ^ 1, (t + 1) << 5);
            asm volatile("s_waitcnt vmcnt(4)" ::: "memory");
        } else {
            asm volatile("s_waitcnt vmcnt(0)" ::: "memory");
        }
        __builtin_amdgcn_sched_barrier(0);
        __builtin_amdgcn_s_barrier();
        short8 a[4], b[4];
#pragma unroll
        for (int mi = 0; mi < 4; ++mi)
            a[mi] = *(const short8*)&As[cur][(wr * 64 + mi * 16 + r) * 32 + kq * 8];
#pragma unroll
        for (int ni = 0; ni < 4; ++ni)
            b[ni] = *(const short8*)&Bs[cur][(wc * 64 + ni * 16 + r) * 32 + kq * 8];
#pragma unroll
        for (int mi = 0; mi < 4; ++mi)
#pragma unroll
            for (int ni = 0; ni < 4; ++ni)
                acc[mi][ni] = __builtin_amdgcn_mfma_f32_16x16x32_bf16(
                    a[mi], b[ni], acc[mi][ni], 0, 0, 0);
    }
    int col_l = lane & 15, row_l = (lane >> 4) * 4;
#pragma unroll
    for (int mi = 0; mi < 4; ++mi)
#pragma unroll
        for (int ni = 0; ni < 4; ++ni) {
            long col = n0 + wc * 64 + ni * 16 + col_l;
            long row0 = m0 + wr * 64 + mi * 16 + row_l;
#pragma unroll
            for (int j = 0; j < 4; ++j) {
                float v = acc[mi][ni][j];
                if constexpr (__is_same(OutT, float))
                    C[(row0 + j) * N + col] = v;
                else
                    C[(row0 + j) * N + col] = __float2bfloat16(v);
            }
        }
}

// ---------------- RMSNorm (per-64) + RoPE, strided bf16 in -> packed bf16 out ----------------
__global__ void norm_rope_kernel(const __hip_bfloat16* __restrict__ buf,
                                 __hip_bfloat16* __restrict__ outb,
                                 const float* __restrict__ freqs,
                                 const float* __restrict__ w, int nvec, int nh,
                                 int tstride, int colbase) {
    int gt = blockIdx.x * blockDim.x + threadIdx.x;
    int gw = gt >> 6;
    int lane = gt & 63;
    if (gw >= nvec) return;
    int t = gw / (nh * 2);
    int rem = gw - t * (nh * 2);
    int s = t & (S_ - 1);
    const __hip_bfloat16* v = buf + (long)t * tstride + colbase + rem * 64;
    float x = __bfloat162float(v[lane]);
    float ss = x * x;
#pragma unroll
    for (int off = 32; off; off >>= 1) ss += __shfl_xor(ss, off);
    float r = rsqrtf(ss * (1.f / 64.f) + 1e-6f);
    x = x * r * w[lane];
    int i = lane >> 1;
    float c  = freqs[(s * (HD_ / 2) + i) * 2];
    float sn = freqs[(s * (HD_ / 2) + i) * 2 + 1];
    float p = __shfl_xor(x, 1);
    float y = (lane & 1) ? fmaf(p, sn, x * c) : fmaf(x, c, -(p * sn));
    outb[(long)gw * 64 + lane] = __float2bfloat16(y);
}

// ---------------- V transpose: qkvb bf16 [t][NCAT] -> vT bf16 [b][kv][d][s] ----------------
__global__ __launch_bounds__(256) void v_transpose_kernel(const short* __restrict__ src,
                                                          short* __restrict__ dst) {
    __shared__ short ls[64][72];
    int s0 = blockIdx.x * 64;
    int kv = blockIdx.y, b = blockIdx.z;
    int tid = threadIdx.x;
    const short* base = src + ((long)(b * S_ + s0)) * NCAT + VOFF + kv * 64;
    {
        int rr = tid >> 2, cc = (tid & 3) * 16;
        *(short8*)&ls[rr][cc]     = *(const short8*)(base + (long)rr * NCAT + cc);
        *(short8*)&ls[rr][cc + 8] = *(const short8*)(base + (long)rr * NCAT + cc + 8);
    }
    __syncthreads();
    short* ob = dst + ((long)(b * KV_ + kv) * 64) * S_ + s0;
    {
        int d = tid >> 2, sl = (tid & 3) * 16;
        short8 o0, o1;
#pragma unroll
        for (int e = 0; e < 8; ++e) { o0[e] = ls[sl + e][d]; o1[e] = ls[sl + 8 + e][d]; }
        *(short8*)(ob + (long)d * S_ + sl)     = o0;
        *(short8*)(ob + (long)d * S_ + sl + 8) = o1;
    }
}

// ---------------- differential causal attention ----------------
// KVBLK=32. K: gload_lds dbuf + source-XOR swizzle; V: reg-staged DOUBLE buffer
// Vt[2][64][40] -> ONE barrier per tile (write(ii+2) ordered after barrier(ii+1)
// which postdates all compute(ii)). V loads stay in flight across barriers
// (vmcnt(2) steady-state: per-wave 2 K-gloads + 1 V-load per tile, uniform).
// k-split pairing: pair p=(qtA=p, qtB=31-p); e=0: qtA full + qtB prefix; e=1: suffix.
__global__ __launch_bounds__(256, 4) void attn_kernel(const short* __restrict__ qb,
                                                      const short* __restrict__ kbuf,
                                                      const short* __restrict__ vtb,
                                                      __hip_bfloat16* __restrict__ ob,
                                                      float* __restrict__ part,
                                                      float* __restrict__ lpart,
                                                      const float* __restrict__ lam_p) {
    __shared__ __align__(16) short Ks[2][32][128];
    __shared__ __align__(16) short Vt[2][64][40];

    int tid = threadIdx.x, w = tid >> 6, lane = tid & 63;
    int b = blockIdx.z, h = blockIdx.y, kv = h / G_;
    int p = (int)blockIdx.x >> 1, e = (int)blockIdx.x & 1;
    int qtA = p, qtB = 31 - p;
    int r = lane & 15, kq = lane >> 4;
    float lam = lam_p[0];

    floatx4 acc[2][4];
    floatx4 accl[2];
    short8 qa[2][2];

    const short* vbase = vtb + (long)(b * KV_ + kv) * 64 * S_;
    // z = log2e*(s - s^3/7500 - 12), s = raw/8:
    const float c1 = 0.18033688f, nc4 = -3.7570e-7f, zoff = -17.3123405f;
    const short one_bf = (short)0x3F80;
    short4v ones4 = {one_bf, one_bf, one_bf, one_bf};

    // K staging: 512 chunks/tile, 2/thread; LDS linear dest; source slot XOR row&7.
    int ch1 = tid + 256;
    int krow0 = tid >> 4, kcs0 = ((tid & 15) ^ (krow0 & 7)) * 8;
    int krow1 = ch1 >> 4, kcs1 = ((ch1 & 15) ^ (krow1 & 7)) * 8;
    const short* kgb = kbuf + ((long)b * S_ * KV_ + kv) * 128;
    int vd = tid >> 2, vch = tid & 3;

    auto issueK = [&](int buf, int ki) {
        long rb = (long)(ki * 32) * (KV_ * 128);
        gload_lds16(kgb + rb + (long)krow0 * (KV_ * 128) + kcs0, &Ks[buf][0][0] + w * 512);
        gload_lds16(kgb + rb + (long)krow1 * (KV_ * 128) + kcs1, &Ks[buf][0][0] + 2048 + w * 512);
    };
    auto loadV = [&](int kb) {
        return *(const short8*)(vbase + (long)vd * S_ + kb + vch * 8);
    };

    auto reset_acc = [&]() {
#pragma unroll
        for (int m = 0; m < 2; ++m) {
            accl[m] = {0.f, 0.f, 0.f, 0.f};
#pragma unroll
            for (int dt = 0; dt < 4; ++dt) acc[m][dt] = {0.f, 0.f, 0.f, 0.f};
        }
    };
    auto load_q = [&](int q0) {
        const short* qrow = qb + ((long)(b * S_ + q0 + r) * H_ + h) * 128;
        qa[0][0] = *(const short8*)(qrow + kq * 8);
        qa[0][1] = *(const short8*)(qrow + 32 + kq * 8);
        qa[1][0] = *(const short8*)(qrow + 64 + kq * 8);
        qa[1][1] = *(const short8*)(qrow + 96 + kq * 8);
    };

    auto tile_compute = [&](int cur, int kb, int q0, bool domask) {
        int rel = q0 + r - kb;
#pragma unroll
        for (int m = 0; m < 2; ++m) {
            floatx4 sacc[2];
#pragma unroll
            for (int nt = 0; nt < 2; ++nt) {
                sacc[nt] = {0.f, 0.f, 0.f, 0.f};
                const short* row = &Ks[cur][nt * 16 + r][0];
                short8 a0 = *(const short8*)(row + (((m * 8) + kq) ^ (r & 7)) * 8);
                short8 a1 = *(const short8*)(row + (((m * 8) + 4 + kq) ^ (r & 7)) * 8);
                sacc[nt] = __builtin_amdgcn_mfma_f32_16x16x32_bf16(a0, qa[m][0], sacc[nt], 0, 0, 0);
                sacc[nt] = __builtin_amdgcn_mfma_f32_16x16x32_bf16(a1, qa[m][1], sacc[nt], 0, 0, 0);
            }
            short4v pa[2];
#pragma unroll
            for (int nt = 0; nt < 2; ++nt) {
                float pv[4];
#pragma unroll
                for (int j = 0; j < 4; ++j) {
                    float raw = sacc[nt][j];
                    float r2 = raw * raw;
                    float z = fmaf(raw, fmaf(r2, nc4, c1), zoff);
                    pv[j] = __builtin_amdgcn_exp2f(z);
                    if (domask && (nt * 16 + kq * 4 + j > rel)) pv[j] = 0.f;
                }
                int lo = cvt_pk_bf16(pv[0], pv[1]);
                int hi = cvt_pk_bf16(pv[2], pv[3]);
                pa[nt] = __builtin_bit_cast(short4v, int2v{lo, hi});
            }
#pragma unroll
            for (int dt = 0; dt < 4; ++dt) {
#pragma unroll
                for (int nt = 0; nt < 2; ++nt) {
                    short4v vb = *(const short4v*)&Vt[cur][dt * 16 + r][nt * 16 + kq * 4];
                    acc[m][dt] = __builtin_amdgcn_mfma_f32_16x16x16bf16_1k(
                        pa[nt], vb, acc[m][dt], 0, 0, 0);
                }
            }
#pragma unroll
            for (int nt = 0; nt < 2; ++nt)
                accl[m] = __builtin_amdgcn_mfma_f32_16x16x16bf16_1k(
                    pa[nt], ones4, accl[m], 0, 0, 0);
        }
    };

    // run over 32-k-tiles [ki0, ki1) of q-tile qt
    auto run = [&](int qt, int ki0, int ki1, bool diag) {
        int q0 = qt * 64 + w * 16;
        load_q(q0);
        reset_acc();
        int nseg = ki1 - ki0;
        issueK(0, ki0);
        short8 rva = loadV(ki0 * 32), rvb;
        for (int ii = 0; ii < nseg; ++ii) {
            int ki = ki0 + ii, cur = ii & 1;
            bool pre = (ii + 1 < nseg);
            if (pre) issueK(cur ^ 1, ki + 1);
            if (pre) asm volatile("s_waitcnt vmcnt(2)" ::: "memory");
            else     asm volatile("s_waitcnt vmcnt(0)" ::: "memory");
            __builtin_amdgcn_sched_barrier(0);
            if (cur == 0) {
                *(short8*)&Vt[0][vd][vch * 8] = rva;
                if (pre) rvb = loadV((ki + 1) * 32);
            } else {
                *(short8*)&Vt[1][vd][vch * 8] = rvb;
                if (pre) rva = loadV((ki + 1) * 32);
            }
            asm volatile("s_waitcnt lgkmcnt(0)" ::: "memory");
            __builtin_amdgcn_sched_barrier(0);
            __builtin_amdgcn_s_barrier();
            tile_compute(cur, ki * 32, q0, diag && ((ki >> 1) == qt));
        }
        __builtin_amdgcn_s_barrier();   // protect LDS reuse across runs
    };

    if (e == 0) {
        run(qtA, 0, 2 * qtA + 2, true);
        {
            int q0 = qtA * 64 + w * 16;
#pragma unroll
            for (int j = 0; j < 4; ++j) {
                float i1 = 1.f / accl[0][j];
                float i2 = lam / accl[1][j];
                int qr = q0 + kq * 4 + j;
                __hip_bfloat16* orow = ob + ((long)(b * S_ + qr) * H_ + h) * 64;
#pragma unroll
                for (int dt = 0; dt < 4; ++dt) {
                    float val = acc[0][dt][j] * i1 - acc[1][dt][j] * i2;
                    orow[dt * 16 + r] = __float2bfloat16(val);
                }
            }
        }
        run(qtB, 0, 31 - 2 * p, false);             // k-prefix of qtB
    } else {
        run(qtB, 31 - 2 * p, 64 - 2 * p, true);     // k-suffix incl diagonal
    }

    // write partial: slot = (b*H+h)*16 + (qtB-16), half = e
    {
        long slot = (long)(b * H_ + h) * 16 + (qtB - 16);
        long base = ((slot * 2 + e) * 2) * 4096L;
        int qloc = w * 16 + kq * 4;
#pragma unroll
        for (int m = 0; m < 2; ++m)
#pragma unroll
            for (int dt = 0; dt < 4; ++dt)
#pragma unroll
                for (int j = 0; j < 4; ++j)
                    part[base + m * 4096L + (qloc + j) * 64 + dt * 16 + r] = acc[m][dt][j];
        if (r == 0) {
#pragma unroll
            for (int m = 0; m < 2; ++m)
#pragma unroll
                for (int j = 0; j < 4; ++j)
                    lpart[((slot * 2 + e) * 2 + m) * 64 + qloc + j] = accl[m][j];
        }
    }
}

// ---------------- merge partials for qt in [16,32) ----------
__global__ __launch_bounds__(256) void attn_merge_kernel(const float* __restrict__ part,
                                                         const float* __restrict__ lpart,
                                                         __hip_bfloat16* __restrict__ ob,
                                                         const float* __restrict__ lam_p) {
    long sid = blockIdx.x;
    int t16 = sid & 15;
    int h = (sid >> 4) & (H_ - 1);
    int b = (int)(sid >> 8);
    int qt = 16 + t16;
    float lam = lam_p[0];
    const float* p0 = part + sid * 4 * 4096L;
    const float* p1 = part + (sid * 4 + 2) * 4096L;
    const float* l0 = lpart + sid * 4 * 64L;
    const float* l1 = lpart + (sid * 4 + 2) * 64L;
    int tid = threadIdx.x;
#pragma unroll
    for (int i = 0; i < 16; ++i) {
        int idx = i * 256 + tid;
        int q = idx >> 6, d = idx & 63;
        float a1 = p0[q * 64 + d] + p1[q * 64 + d];
        float a2 = p0[4096 + q * 64 + d] + p1[4096 + q * 64 + d];
        float L1 = l0[q] + l1[q];
        float L2 = l0[64 + q] + l1[64 + q];
        float val = a1 / L1 - lam * (a2 / L2);
        ob[((long)(b * S_ + qt * 64 + q) * H_ + h) * 64 + d] = __float2bfloat16(val);
    }
}

// ---------------- launch ----------------
extern "C" void kernel_launch(void* const* d_in, const int* in_sizes, int n_in,
                              void* d_out, int out_size, void* d_ws, size_t ws_size,
                              hipStream_t stream) {
    const float* x     = (const float*)d_in[0];
    const float* freqs = (const float*)d_in[1];
    const float* wq    = (const float*)d_in[2];
    const float* wk    = (const float*)d_in[3];
    const float* wv    = (const float*)d_in[4];
    const float* wo    = (const float*)d_in[5];
    const float* qnw   = (const float*)d_in[6];
    const float* knw   = (const float*)d_in[7];
    const float* lam   = (const float*)d_in[8];
    float* out = (float*)d_out;

    const int T = B_ * S_;
    char* ws = (char*)d_ws;
    size_t off = 0;
    auto alloc = [&](size_t bytes) {
        void* p = ws + off;
        off += (bytes + 255) & ~(size_t)255;
        return p;
    };
    __hip_bfloat16* xb   = (__hip_bfloat16*)alloc((size_t)T * D_ * 2);
    __hip_bfloat16* wcat = (__hip_bfloat16*)alloc((size_t)NCAT * D_ * 2);
    __hip_bfloat16* wob  = (__hip_bfloat16*)alloc((size_t)D_ * D_ * 2);
    __hip_bfloat16* qkvb = (__hip_bfloat16*)alloc((size_t)T * NCAT * 2);
    __hip_bfloat16* qb16 = (__hip_bfloat16*)alloc((size_t)T * 2 * H_ * HD_ * 2);
    __hip_bfloat16* kb16 = (__hip_bfloat16*)alloc((size_t)T * 2 * KV_ * HD_ * 2);
    __hip_bfloat16* vT   = (__hip_bfloat16*)alloc((size_t)B_ * KV_ * HD_ * S_ * 2);
    float* part  = (float*)alloc((size_t)512 * 2 * 2 * 4096 * 4);
    float* lpart = (float*)alloc((size_t)512 * 2 * 2 * 64 * 4);
    __hip_bfloat16* aob  = xb;

    // fused cvt: x, wq, wk, wv, wo (wcat segments are contiguous)
    cvt5_kernel<<<dim3(2048, 5), 256, 0, stream>>>(
        x, wq, wk, wv, wo,
        xb, wcat, wcat + (size_t)2 * H_ * HD_ * D_,
        wcat + (size_t)(2 * H_ * HD_ + 2 * KV_ * HD_) * D_, wob,
        T * D_, 2 * H_ * HD_ * D_, 2 * KV_ * HD_ * D_, KV_ * HD_ * D_, D_ * D_);

    gemm_bt_lds<__hip_bfloat16><<<dim3(NCAT / 128, T / 128), 256, 0, stream>>>(
        (const short*)xb, (const short*)wcat, qkvb, T, NCAT, D_);

    {
        int nvq = T * H_ * 2;
        norm_rope_kernel<<<(nvq * 64 + 255) / 256, 256, 0, stream>>>(
            qkvb, qb16, freqs, qnw, nvq, H_, NCAT, 0);
        int nvk = T * KV_ * 2;
        norm_rope_kernel<<<(nvk * 64 + 255) / 256, 256, 0, stream>>>(
            qkvb, kb16, freqs, knw, nvk, KV_, NCAT, 2 * H_ * HD_);
        v_transpose_kernel<<<dim3(S_ / 64, KV_, B_), 256, 0, stream>>>(
            (const short*)qkvb, (short*)vT);
    }

    attn_kernel<<<dim3(32, H_, B_), 256, 0, stream>>>(
        (const short*)qb16, (const short*)kb16, (const short*)vT, aob, part, lpart, lam);
    attn_merge_kernel<<<512, 256, 0, stream>>>(part, lpart, aob, lam);

    gemm_bt_lds<float><<<dim3(D_ / 128, T / 128), 256, 0, stream>>>(
        (const short*)aob, (const short*)wob, out, T, D_, D_);
}